// Round 9
// baseline (152.684 us; speedup 1.0000x reference)
//
#include <hip/hip_runtime.h>
#include <stdint.h>

#define S_LEN 2048
#define EMB   768
#define NH    12
#define DH    64
#define M_TOT 4096                 // B*S
#define WELEM 589824               // 768*768
#define QELEM 3145728              // 4096*768

typedef float  floatx4  __attribute__((ext_vector_type(4)));
typedef float  floatx16 __attribute__((ext_vector_type(16)));
typedef __bf16 bf16x8  __attribute__((ext_vector_type(8)));
typedef __bf16 bf16x4  __attribute__((ext_vector_type(4)));
typedef unsigned short ushortx4 __attribute__((ext_vector_type(4)));

__device__ __forceinline__ unsigned short f2bf(float f) {
    union { float f; unsigned u; } v; v.f = f;
    unsigned u = v.u;
    unsigned r = (u + 0x7FFFu + ((u >> 16) & 1u)) >> 16;   // RNE
    return (unsigned short)r;
}

__device__ __forceinline__ void gl_lds16(const void* g, void* l) {
    __builtin_amdgcn_global_load_lds(
        (__attribute__((address_space(1))) const void*)g,
        (__attribute__((address_space(3))) void*)l, 16, 0, 0);
}

// ---------------- merged converts: x fp32->bf16 (blocks 0..3071), W transpose (3072..3647),
// ---------------- RoPE cos/sin table (3648..3903): tab[s][d] = {cos, sin}(s * 10000^(-d/32))
__global__ void cvt_all_kernel(const float* __restrict__ x, unsigned short* __restrict__ xb,
                               const float* __restrict__ W0, const float* __restrict__ W1,
                               const float* __restrict__ W2, const float* __restrict__ W3,
                               unsigned short* __restrict__ WT_all, float2* __restrict__ rope) {
    __shared__ float t[64][65];
    const int blk = blockIdx.x;
    if (blk < 3072) {
        int i = (blk * 256 + threadIdx.x) * 4;
        float4 v = *(const float4*)(x + i);
        ushortx4 r = { f2bf(v.x), f2bf(v.y), f2bf(v.z), f2bf(v.w) };
        *(ushortx4*)(xb + i) = r;
        return;
    }
    if (blk >= 3648) {
        int idx = (blk - 3648) * 256 + threadIdx.x;      // 65536 = 2048 * 32
        int s = idx >> 5, d = idx & 31;
        float f = exp2f((float)d * -0.41524101186092034f);  // 10000^(-d/32)
        float th = (float)s * f;
        float sn, cs; sincosf(th, &sn, &cs);
        rope[idx] = make_float2(cs, sn);
        return;
    }
    const int tc = blk - 3072;
    const int z = tc / 144, rr0 = tc % 144;
    const float* W = (z == 0) ? W0 : (z == 1 ? W1 : (z == 2 ? W2 : W3));
    unsigned short* O = WT_all + (size_t)z * WELEM;
    const int k0 = (rr0 % 12) * 64, n0 = (rr0 / 12) * 64;
    const int c = threadIdx.x & 63, r4 = threadIdx.x >> 6;
#pragma unroll
    for (int rr = 0; rr < 64; rr += 4) {
        int r = rr + r4;
        t[r][c] = W[(size_t)(k0 + r) * EMB + n0 + c];
    }
    __syncthreads();
#pragma unroll
    for (int rr = 0; rr < 64; rr += 4) {
        int nn = rr + r4;
        O[(size_t)(n0 + nn) * EMB + k0 + c] = f2bf(t[c][nn]);
    }
}

// ---------------- templated GEMM core: C(BMxBN) = A(M,K)*BT(N,K)^T, bf16 MFMA ----------------
template<int BM, int BN, int WM, int WN>
static __device__ __forceinline__ void gemm_core(
    const unsigned short* __restrict__ A, const unsigned short* __restrict__ BT,
    int m0, int n0, int K, int tid, floatx4 (&acc)[WM / 16][WN / 16],
    unsigned short* Als, unsigned short* Bls)
{
    const int lane = tid & 63;
    const int c0 = lane & 15, quad = lane >> 4;
    const int wave = tid >> 6;
    const int NWN = BN / WN;
    const int wm = (wave / NWN) * WM, wn = (wave % NWN) * WN;

    for (int k0 = 0; k0 < K; k0 += 64) {
        __syncthreads();
#pragma unroll
        for (int it = 0; it < BM / 32; ++it) {   // A: 256 thr x 16B = 32 rows of 64 per round
            int ch = it * 256 + tid;
            int row = ch >> 3, sc = ch & 7;
            int cc = sc ^ (row & 7);
            gl_lds16(A + (size_t)(m0 + row) * K + k0 + cc * 8, Als + ch * 8);
        }
#pragma unroll
        for (int it = 0; it < BN / 32; ++it) {   // B
            int ch = it * 256 + tid;
            int row = ch >> 3, sc = ch & 7;
            int cc = sc ^ (row & 7);
            gl_lds16(BT + (size_t)(n0 + row) * K + k0 + cc * 8, Bls + ch * 8);
        }
        __syncthreads();
        bf16x8 af[WM / 16][2], bfv[WN / 16][2];
#pragma unroll
        for (int ii = 0; ii < WM / 16; ++ii) {
            int row = wm + 16 * ii + c0;
#pragma unroll
            for (int h = 0; h < 2; ++h)
                af[ii][h] = *(const bf16x8*)(Als + row * 64 + (((4 * h + quad) ^ (row & 7)) * 8));
        }
#pragma unroll
        for (int jj = 0; jj < WN / 16; ++jj) {
            int row = wn + 16 * jj + c0;
#pragma unroll
            for (int h = 0; h < 2; ++h)
                bfv[jj][h] = *(const bf16x8*)(Bls + row * 64 + (((4 * h + quad) ^ (row & 7)) * 8));
        }
#pragma unroll
        for (int ii = 0; ii < WM / 16; ++ii)
#pragma unroll
            for (int jj = 0; jj < WN / 16; ++jj) {
                acc[ii][jj] = __builtin_amdgcn_mfma_f32_16x16x32_bf16(af[ii][0], bfv[jj][0], acc[ii][jj], 0, 0, 0);
                acc[ii][jj] = __builtin_amdgcn_mfma_f32_16x16x32_bf16(af[ii][1], bfv[jj][1], acc[ii][jj], 0, 0, 0);
            }
    }
}

// ---------------- QKV GEMM + bias (+RoPE for Q,K via table); V written transposed ----------------
// 64x128 tiles -> grid 64x6x3 = 1152 blocks (~4.5 blocks/CU).
__global__ __launch_bounds__(256, 4) void qkv_kernel(
    const unsigned short* __restrict__ xb, const unsigned short* __restrict__ WT_all,
    const float* __restrict__ bq, const float* __restrict__ bk, const float* __restrict__ bv,
    const float2* __restrict__ rope, unsigned short* __restrict__ qkv_out)
{
    __shared__ __align__(16) unsigned short Als[64 * 64];
    __shared__ __align__(16) unsigned short Bls[128 * 64];
    const int z = blockIdx.z;
    const float* bias = (z == 0) ? bq : (z == 1 ? bk : bv);
    __bf16* Cout = (__bf16*)(qkv_out + (size_t)z * QELEM);
    const int m0 = blockIdx.x * 64, n0 = blockIdx.y * 128;
    const int tid = threadIdx.x, lane = tid & 63, c0 = lane & 15, quad = lane >> 4, wave = tid >> 6;
    const int wm = (wave >> 1) * 32, wn = (wave & 1) * 64;

    floatx4 acc[2][4] = {};
    gemm_core<64, 128, 32, 64>(xb, WT_all + (size_t)z * WELEM, m0, n0, EMB, tid, acc, Als, Bls);

    if (z == 2) {
#pragma unroll
        for (int ii = 0; ii < 2; ++ii) {
            int m = m0 + wm + 16 * ii + quad * 4;
            int b = m >> 11, s = m & (S_LEN - 1);
#pragma unroll
            for (int jj = 0; jj < 4; ++jj) {
                int n = n0 + wn + 16 * jj + c0;
                int h = n >> 6, d = n & 63;
                float bn = bias[n];
                bf16x4 pv;
#pragma unroll
                for (int r = 0; r < 4; ++r) pv[r] = (__bf16)(acc[ii][jj][r] + bn);
                *(bf16x4*)(Cout + ((size_t)(b * NH + h) * DH + d) * S_LEN + s) = pv;   // V^T: (BH,D,S)
            }
        }
        return;
    }

#pragma unroll
    for (int ii = 0; ii < 2; ++ii) {
#pragma unroll
        for (int r = 0; r < 4; ++r) {
            int m = m0 + wm + 16 * ii + quad * 4 + r;
            int b = m >> 11, s = m & (S_LEN - 1);
            float vals[4];
#pragma unroll
            for (int jj = 0; jj < 4; ++jj) vals[jj] = acc[ii][jj][r] + bias[n0 + wn + 16 * jj + c0];
#pragma unroll
            for (int jj = 0; jj < 2; ++jj) {
                int d = 16 * jj + c0;
                float2 t = rope[s * 32 + d];       // {cos, sin}, precomputed
                float lo = vals[jj], hi = vals[jj + 2];
                vals[jj]     = lo * t.x - hi * t.y;
                vals[jj + 2] = hi * t.x + lo * t.y;
            }
            if (z == 0) {           // fold 1/sqrt(D) * log2(e) into Q
#pragma unroll
                for (int jj = 0; jj < 4; ++jj) vals[jj] *= 0.18033688011112042f;
            }
#pragma unroll
            for (int jj = 0; jj < 4; ++jj) {
                int n = n0 + wn + 16 * jj + c0;
                int h = n >> 6, d = n & 63;
                Cout[((size_t)(b * NH + h) * S_LEN + s) * DH + d] = (__bf16)vals[jj];   // (BH,S,D)
            }
        }
    }
}

// ---------------- causal flash attention, 32x32 MFMA, chain-split ILP version ----------------
// Latency-chain fixes vs R6/R8: QK^T = two independent 2-MFMA chains + add; PV = four
// persistent accumulators (one MFMA each per tile, merged at end); l = 4 partial sums.
__global__ __launch_bounds__(256, 3) void flash_kernel(
    const unsigned short* __restrict__ Qg, const unsigned short* __restrict__ Kg,
    const unsigned short* __restrict__ Vt, unsigned short* __restrict__ Og)
{
    __shared__ __align__(16) unsigned short Kls[3][64 * 64];   // [s][d], chunk-swizzled
    __shared__ __align__(16) unsigned short Vls[3][64 * 64];   // [d][s], chunk-swizzled
    __shared__ float lred[2][64];

    // snake schedule: CU triples {i, i+256, i+512} get ~equal causal work
    const int i = blockIdx.x;
    const int kk = i >> 8, g = i & 255;
    const int r0 = (kk == 0) ? g : (kk == 1 ? 511 - g : 512 + g);
    const int qt = 31 - r0 / 24;
    const int bh = r0 % 24;
    const int b = bh / NH, h = bh % NH;
    const int m0 = qt * 64;
    const int tid = threadIdx.x, lane = tid & 63, wave = tid >> 6;
    const int wm2 = wave >> 1, wn2 = wave & 1;
    const int lr = lane & 31, hf = lane >> 5;
    const size_t base = (size_t)bh * S_LEN * DH;
    const int mrow = m0 + wm2 * 32 + lr;      // this lane's m (S column / Q row)

    // Q-frags (B-operand of 32x32x16): col m = lr, k = d = 16t + 8*hf + j
    bf16x8 qf[4];
#pragma unroll
    for (int t = 0; t < 4; ++t)
        qf[t] = *(const bf16x8*)(Qg + base + (size_t)mrow * DH + 16 * t + 8 * hf);
    asm volatile("" :: "v"(qf[0]), "v"(qf[1]), "v"(qf[2]), "v"(qf[3]));

    // PV accumulators: 4 independent (dt x t2), merged after the loop.
    floatx16 oa0a = {}, oa0b = {}, oa1a = {}, oa1b = {};
    float l0 = 0.f, l1 = 0.f, l2 = 0.f, l3 = 0.f;   // 4 partial row-sums
    const float C = 23.083120654223414f;       // 16*log2(e): constant "max" (scores bounded << 16)
    const int ntiles = qt + 1;

    // stage: 4 gl_lds16 per thread per tile (2 K + 2 V) — the vmcnt bookkeeping unit
#define STAGE_TILE(T, BUF)                                                              \
    {                                                                                   \
        _Pragma("unroll")                                                               \
        for (int it = 0; it < 2; ++it) {                                                \
            int ch = it * 256 + tid;                                                    \
            int row = ch >> 3, cc = (ch & 7) ^ (row & 7);                               \
            gl_lds16(Kg + base + (size_t)((T) * 64 + row) * DH + cc * 8,                \
                     &Kls[BUF][ch * 8]);                                                \
            gl_lds16(Vt + base + (size_t)row * S_LEN + (T) * 64 + cc * 8,               \
                     &Vls[BUF][ch * 8]);                                                \
        }                                                                               \
    }

    STAGE_TILE(0, 0);
    if (ntiles > 1) STAGE_TILE(1, 1);

    for (int nt = 0; nt < ntiles; ++nt) {
        const int buf = nt % 3;
        if (nt + 1 < ntiles) asm volatile("s_waitcnt vmcnt(4)" ::: "memory");
        else                 asm volatile("s_waitcnt vmcnt(0)" ::: "memory");
        __builtin_amdgcn_s_barrier();          // all waves' stage(nt) landed
        asm volatile("" ::: "memory");         // fence: no LDS reads/stage hoisted above
        if (nt + 2 < ntiles) STAGE_TILE(nt + 2, (nt + 2) % 3);
        const unsigned short* Kb = Kls[buf];
        const unsigned short* Vb = Vls[buf];

        // S^T chunk = K(32n) · Q^T(32m): TWO independent 2-MFMA chains, then one add.
        floatx16 sa_a = {}, sa_b = {};
        __builtin_amdgcn_s_setprio(1);
#pragma unroll
        for (int t = 0; t < 2; ++t) {
            int row = wn2 * 32 + lr;
            int cka = (2 * t + hf) ^ (row & 7);
            int ckb = (2 * (t + 2) + hf) ^ (row & 7);
            bf16x8 kfa = *(const bf16x8*)(Kb + row * 64 + cka * 8);
            bf16x8 kfb = *(const bf16x8*)(Kb + row * 64 + ckb * 8);
            sa_a = __builtin_amdgcn_mfma_f32_32x32x16_bf16(kfa, qf[t],     sa_a, 0, 0, 0);
            sa_b = __builtin_amdgcn_mfma_f32_32x32x16_bf16(kfb, qf[t + 2], sa_b, 0, 0, 0);
        }
        __builtin_amdgcn_s_setprio(0);
        floatx16 sa = sa_a + sa_b;

        if (nt == ntiles - 1) {                // causal mask, diagonal tile only
#pragma unroll
            for (int r = 0; r < 16; ++r) {
                int n = nt * 64 + wn2 * 32 + (r & 3) + 8 * (r >> 2) + 4 * hf;
                if (n > mrow) sa[r] = -1e30f;
            }
        }

        // p = exp2(s - C) packed straight to bf16 word-pairs (n ascending in r); 4 l-partials
        unsigned W[8];
#pragma unroll
        for (int q = 0; q < 8; ++q) {
            float p0 = __builtin_amdgcn_exp2f(sa[2 * q] - C);
            float p1 = __builtin_amdgcn_exp2f(sa[2 * q + 1] - C);
            if ((q & 3) == 0)      l0 += p0 + p1;
            else if ((q & 3) == 1) l1 += p0 + p1;
            else if ((q & 3) == 2) l2 += p0 + p1;
            else                   l3 += p0 + p1;
            union { __bf16 bb[2]; unsigned u; } w;
            w.bb[0] = (__bf16)p0; w.bb[1] = (__bf16)p1;
            W[q] = w.u;
        }
        // PV B-frags: k = n_local = 16*t2 + 8*hf + j. Half-swap via shfl_xor(32).
        bf16x8 pb[2];
#pragma unroll
        for (int t2 = 0; t2 < 2; ++t2) {
            unsigned own0 = hf ? W[4 * t2 + 2] : W[4 * t2 + 0];
            unsigned own1 = hf ? W[4 * t2 + 3] : W[4 * t2 + 1];
            unsigned giv0 = hf ? W[4 * t2 + 0] : W[4 * t2 + 2];
            unsigned giv1 = hf ? W[4 * t2 + 1] : W[4 * t2 + 3];
            unsigned s0 = (unsigned)__shfl_xor((int)giv0, 32, 64);
            unsigned s1 = (unsigned)__shfl_xor((int)giv1, 32, 64);
            union { unsigned u[4]; bf16x8 v; } pk;
            pk.u[0] = hf ? s0 : own0;          // words from half 0
            pk.u[1] = hf ? s1 : own1;
            pk.u[2] = hf ? own0 : s0;          // words from half 1
            pk.u[3] = hf ? own1 : s1;
            pb[t2] = pk.v;
        }

        // O^T += V^T · P: 4 INDEPENDENT accumulators, one MFMA each (no intra-tile chain).
        __builtin_amdgcn_s_setprio(1);
        {
            int d0 = lr, d1 = 32 + lr;
            int cv00 = (wn2 * 4 + hf) ^ (d0 & 7);
            int cv01 = (wn2 * 4 + 2 + hf) ^ (d0 & 7);
            int cv10 = (wn2 * 4 + hf) ^ (d1 & 7);
            int cv11 = (wn2 * 4 + 2 + hf) ^ (d1 & 7);
            bf16x8 vf00 = *(const bf16x8*)(Vb + d0 * 64 + cv00 * 8);
            bf16x8 vf01 = *(const bf16x8*)(Vb + d0 * 64 + cv01 * 8);
            bf16x8 vf10 = *(const bf16x8*)(Vb + d1 * 64 + cv10 * 8);
            bf16x8 vf11 = *(const bf16x8*)(Vb + d1 * 64 + cv11 * 8);
            oa0a = __builtin_amdgcn_mfma_f32_32x32x16_bf16(vf00, pb[0], oa0a, 0, 0, 0);
            oa0b = __builtin_amdgcn_mfma_f32_32x32x16_bf16(vf01, pb[1], oa0b, 0, 0, 0);
            oa1a = __builtin_amdgcn_mfma_f32_32x32x16_bf16(vf10, pb[0], oa1a, 0, 0, 0);
            oa1b = __builtin_amdgcn_mfma_f32_32x32x16_bf16(vf11, pb[1], oa1b, 0, 0, 0);
        }
        __builtin_amdgcn_s_setprio(0);
    }
#undef STAGE_TILE

    // merge split accumulators and l partials
    floatx16 oa0 = oa0a + oa0b;
    floatx16 oa1 = oa1a + oa1b;
    float l_lane = (l0 + l1) + (l2 + l3);
    l_lane += __shfl_xor(l_lane, 32, 64);      // lanes l and l^32: same m, disjoint n

    // cross-wave (wn2 pair) O/l reduction via LDS scratch (aliases Kls; all staging done)
    __syncthreads();
    float* red = (float*)&Kls[0][0];           // [64][64] f32 = 16KB
    if (wn2 == 1) {
#pragma unroll
        for (int e = 0; e < 16; ++e) red[(wm2 * 32 + e) * 64 + lane]        = oa0[e];
#pragma unroll
        for (int e = 0; e < 16; ++e) red[(wm2 * 32 + 16 + e) * 64 + lane]   = oa1[e];
        lred[wm2][lane] = l_lane;
    }
    __syncthreads();
    if (wn2 == 0) {
        const float lt = l_lane + lred[wm2][lane];
        const float rl = 1.0f / lt;
        __bf16* Ob16 = (__bf16*)Og;
#pragma unroll
        for (int rg = 0; rg < 4; ++rg) {       // reg groups of 4: d = 8*rg + 4*hf (+32 for oa1)
            bf16x4 ov0, ov1;
#pragma unroll
            for (int j = 0; j < 4; ++j) {
                int e = rg * 4 + j;
                ov0[j] = (__bf16)((oa0[e] + red[(wm2 * 32 + e) * 64 + lane]) * rl);
                ov1[j] = (__bf16)((oa1[e] + red[(wm2 * 32 + 16 + e) * 64 + lane]) * rl);
            }
            int d = 8 * rg + 4 * hf;
            *(bf16x4*)(Ob16 + ((size_t)(b * S_LEN + mrow)) * EMB + h * DH + d)      = ov0;
            *(bf16x4*)(Ob16 + ((size_t)(b * S_LEN + mrow)) * EMB + h * DH + 32 + d) = ov1;
        }
    }
}

// ---------------- output projection: fp32 out; 64x64 tiles -> 768 blocks (3/CU) ----------------
__global__ __launch_bounds__(256, 4) void proj_kernel(
    const unsigned short* __restrict__ Ob, const unsigned short* __restrict__ WpT,
    const float* __restrict__ bp, float* __restrict__ out)
{
    __shared__ __align__(16) unsigned short Als[64 * 64];
    __shared__ __align__(16) unsigned short Bls[64 * 64];
    const int m0 = blockIdx.x * 64, n0 = blockIdx.y * 64;
    const int tid = threadIdx.x, lane = tid & 63, c0 = lane & 15, quad = lane >> 4, wave = tid >> 6;
    const int wm = (wave >> 1) * 32, wn = (wave & 1) * 32;

    floatx4 acc[2][2] = {};
    gemm_core<64, 64, 32, 32>(Ob, WpT, m0, n0, EMB, tid, acc, Als, Bls);

#pragma unroll
    for (int ii = 0; ii < 2; ++ii)
#pragma unroll
        for (int r = 0; r < 4; ++r) {
            int m = m0 + wm + 16 * ii + quad * 4 + r;
#pragma unroll
            for (int jj = 0; jj < 2; ++jj) {
                int n = n0 + wn + 16 * jj + c0;
                out[(size_t)m * EMB + n] = acc[ii][jj][r] + bp[n];
            }
        }
}

extern "C" void kernel_launch(void* const* d_in, const int* in_sizes, int n_in,
                              void* d_out, int out_size, void* d_ws, size_t ws_size,
                              hipStream_t stream)
{
    (void)in_sizes; (void)n_in; (void)out_size;
    const float* x  = (const float*)d_in[0];
    const float* Wq = (const float*)d_in[1];
    const float* bq = (const float*)d_in[2];
    const float* Wk = (const float*)d_in[3];
    const float* bk = (const float*)d_in[4];
    const float* Wv = (const float*)d_in[5];
    const float* bv = (const float*)d_in[6];
    const float* Wp = (const float*)d_in[7];
    const float* bp = (const float*)d_in[8];

    unsigned short* ws  = (unsigned short*)d_ws;
    unsigned short* xb  = ws;                                   // QELEM
    unsigned short* WT  = xb + (size_t)QELEM;                   // 4*WELEM  (WqT,WkT,WvT,WpT)
    unsigned short* QKV = WT + 4 * (size_t)WELEM;               // 3*QELEM  (Q,K,V^T)
    unsigned short* Ob  = QKV + 3 * (size_t)QELEM;              // QELEM
    float2* rope = (float2*)(Ob + (size_t)QELEM);               // 2048*32 float2 = 512KB
    if (ws_size < ((size_t)QELEM * 5 + 4 * (size_t)WELEM) * 2 + 2048 * 32 * 8) return;

    cvt_all_kernel<<<3904, 256, 0, stream>>>(x, xb, Wq, Wk, Wv, Wp, WT, rope);
    qkv_kernel<<<dim3(64, 6, 3), 256, 0, stream>>>(xb, WT, bq, bk, bv, (const float2*)rope, QKV);
    flash_kernel<<<dim3(768), 256, 0, stream>>>(QKV, QKV + QELEM, QKV + 2 * (size_t)QELEM, Ob);
    proj_kernel<<<dim3(64, 12), 256, 0, stream>>>(Ob, WT + 3 * (size_t)WELEM, bp, (float*)d_out);
}

// Round 10
// 149.690 us; speedup vs baseline: 1.0200x; 1.0200x over previous
//
#include <hip/hip_runtime.h>
#include <stdint.h>

#define S_LEN 2048
#define EMB   768
#define NH    12
#define DH    64
#define M_TOT 4096                 // B*S
#define WELEM 589824               // 768*768
#define QELEM 3145728              // 4096*768

typedef float  floatx4  __attribute__((ext_vector_type(4)));
typedef float  floatx16 __attribute__((ext_vector_type(16)));
typedef __bf16 bf16x8  __attribute__((ext_vector_type(8)));
typedef __bf16 bf16x4  __attribute__((ext_vector_type(4)));
typedef unsigned short ushortx4 __attribute__((ext_vector_type(4)));

__device__ __forceinline__ unsigned short f2bf(float f) {
    union { float f; unsigned u; } v; v.f = f;
    unsigned u = v.u;
    unsigned r = (u + 0x7FFFu + ((u >> 16) & 1u)) >> 16;   // RNE
    return (unsigned short)r;
}

__device__ __forceinline__ void gl_lds16(const void* g, void* l) {
    __builtin_amdgcn_global_load_lds(
        (__attribute__((address_space(1))) const void*)g,
        (__attribute__((address_space(3))) void*)l, 16, 0, 0);
}

// ---------------- merged converts: x fp32->bf16 (blocks 0..3071), W transpose (3072..3647),
// ---------------- RoPE cos/sin table (3648..3903): tab[s][d] = {cos, sin}(s * 10000^(-d/32))
__global__ void cvt_all_kernel(const float* __restrict__ x, unsigned short* __restrict__ xb,
                               const float* __restrict__ W0, const float* __restrict__ W1,
                               const float* __restrict__ W2, const float* __restrict__ W3,
                               unsigned short* __restrict__ WT_all, float2* __restrict__ rope) {
    __shared__ float t[64][65];
    const int blk = blockIdx.x;
    if (blk < 3072) {
        int i = (blk * 256 + threadIdx.x) * 4;
        float4 v = *(const float4*)(x + i);
        ushortx4 r = { f2bf(v.x), f2bf(v.y), f2bf(v.z), f2bf(v.w) };
        *(ushortx4*)(xb + i) = r;
        return;
    }
    if (blk >= 3648) {
        int idx = (blk - 3648) * 256 + threadIdx.x;      // 65536 = 2048 * 32
        int s = idx >> 5, d = idx & 31;
        float f = exp2f((float)d * -0.41524101186092034f);  // 10000^(-d/32)
        float th = (float)s * f;
        float sn, cs; sincosf(th, &sn, &cs);
        rope[idx] = make_float2(cs, sn);
        return;
    }
    const int tc = blk - 3072;
    const int z = tc / 144, rr0 = tc % 144;
    const float* W = (z == 0) ? W0 : (z == 1 ? W1 : (z == 2 ? W2 : W3));
    unsigned short* O = WT_all + (size_t)z * WELEM;
    const int k0 = (rr0 % 12) * 64, n0 = (rr0 / 12) * 64;
    const int c = threadIdx.x & 63, r4 = threadIdx.x >> 6;
#pragma unroll
    for (int rr = 0; rr < 64; rr += 4) {
        int r = rr + r4;
        t[r][c] = W[(size_t)(k0 + r) * EMB + n0 + c];
    }
    __syncthreads();
#pragma unroll
    for (int rr = 0; rr < 64; rr += 4) {
        int nn = rr + r4;
        O[(size_t)(n0 + nn) * EMB + k0 + c] = f2bf(t[c][nn]);
    }
}

// ---------------- templated GEMM core (used by proj): C(BMxBN) = A*BT^T ----------------
template<int BM, int BN, int WM, int WN>
static __device__ __forceinline__ void gemm_core(
    const unsigned short* __restrict__ A, const unsigned short* __restrict__ BT,
    int m0, int n0, int K, int tid, floatx4 (&acc)[WM / 16][WN / 16],
    unsigned short* Als, unsigned short* Bls)
{
    const int lane = tid & 63;
    const int c0 = lane & 15, quad = lane >> 4;
    const int wave = tid >> 6;
    const int NWN = BN / WN;
    const int wm = (wave / NWN) * WM, wn = (wave % NWN) * WN;

    for (int k0 = 0; k0 < K; k0 += 64) {
        __syncthreads();
#pragma unroll
        for (int it = 0; it < BM / 32; ++it) {
            int ch = it * 256 + tid;
            int row = ch >> 3, sc = ch & 7;
            int cc = sc ^ (row & 7);
            gl_lds16(A + (size_t)(m0 + row) * K + k0 + cc * 8, Als + ch * 8);
        }
#pragma unroll
        for (int it = 0; it < BN / 32; ++it) {
            int ch = it * 256 + tid;
            int row = ch >> 3, sc = ch & 7;
            int cc = sc ^ (row & 7);
            gl_lds16(BT + (size_t)(n0 + row) * K + k0 + cc * 8, Bls + ch * 8);
        }
        __syncthreads();
        bf16x8 af[WM / 16][2], bfv[WN / 16][2];
#pragma unroll
        for (int ii = 0; ii < WM / 16; ++ii) {
            int row = wm + 16 * ii + c0;
#pragma unroll
            for (int h = 0; h < 2; ++h)
                af[ii][h] = *(const bf16x8*)(Als + row * 64 + (((4 * h + quad) ^ (row & 7)) * 8));
        }
#pragma unroll
        for (int jj = 0; jj < WN / 16; ++jj) {
            int row = wn + 16 * jj + c0;
#pragma unroll
            for (int h = 0; h < 2; ++h)
                bfv[jj][h] = *(const bf16x8*)(Bls + row * 64 + (((4 * h + quad) ^ (row & 7)) * 8));
        }
#pragma unroll
        for (int ii = 0; ii < WM / 16; ++ii)
#pragma unroll
            for (int jj = 0; jj < WN / 16; ++jj) {
                acc[ii][jj] = __builtin_amdgcn_mfma_f32_16x16x32_bf16(af[ii][0], bfv[jj][0], acc[ii][jj], 0, 0, 0);
                acc[ii][jj] = __builtin_amdgcn_mfma_f32_16x16x32_bf16(af[ii][1], bfv[jj][1], acc[ii][jj], 0, 0, 0);
            }
    }
}

// ---------------- z-FUSED QKV GEMM: 64m x 64n x 3z per block, grid 64x12 = 768 (3/CU) --------
// One A (xb) stage serves all three weight panels: 8 stage-rounds -> 24 MFMAs per k-step
// (vs 6 -> 16 before); A-panel traffic cut 3x. Wave n-tiles remapped to {16*wn2, 16*wn2+32}
// so each RoPE pair (d, d+32) stays lane-local. Q gets 0.125*log2(e) folded in.
__global__ __launch_bounds__(256, 3) void qkv_kernel(
    const unsigned short* __restrict__ xb, const unsigned short* __restrict__ WT_all,
    const float* __restrict__ bq, const float* __restrict__ bk, const float* __restrict__ bv,
    const float2* __restrict__ rope, unsigned short* __restrict__ qkv_out)
{
    __shared__ __align__(16) unsigned short Als[64 * 64];
    __shared__ __align__(16) unsigned short Bls[3][64 * 64];
    const int m0 = blockIdx.x * 64, n0 = blockIdx.y * 64;
    const int tid = threadIdx.x, lane = tid & 63, c0 = lane & 15, quad = lane >> 4, wave = tid >> 6;
    const int wm = (wave >> 1) * 32, wn2 = wave & 1;
    const int h = n0 >> 6;                      // whole block is one head-column

    floatx4 acc[3][2][2] = {};

    for (int k0 = 0; k0 < EMB; k0 += 64) {
        __syncthreads();
#pragma unroll
        for (int it = 0; it < 2; ++it) {        // A: 64x64 bf16 = 2 rounds
            int ch = it * 256 + tid;
            int row = ch >> 3, cc = (ch & 7) ^ (row & 7);
            gl_lds16(xb + (size_t)(m0 + row) * EMB + k0 + cc * 8, Als + ch * 8);
        }
#pragma unroll
        for (int z = 0; z < 3; ++z)
#pragma unroll
            for (int it = 0; it < 2; ++it) {    // B: 3 panels x 2 rounds
                int ch = it * 256 + tid;
                int row = ch >> 3, cc = (ch & 7) ^ (row & 7);
                gl_lds16(WT_all + (size_t)z * WELEM + (size_t)(n0 + row) * EMB + k0 + cc * 8,
                         &Bls[z][ch * 8]);
            }
        __syncthreads();
        bf16x8 af[2][2];
#pragma unroll
        for (int ii = 0; ii < 2; ++ii) {
            int row = wm + 16 * ii + c0;
#pragma unroll
            for (int hh = 0; hh < 2; ++hh)
                af[ii][hh] = *(const bf16x8*)(Als + row * 64 + (((4 * hh + quad) ^ (row & 7)) * 8));
        }
#pragma unroll
        for (int z = 0; z < 3; ++z) {
#pragma unroll
            for (int jj = 0; jj < 2; ++jj) {
                int row = 16 * wn2 + 32 * jj + c0;     // n-tiles {wn2, wn2+2}: rope-pair local
                bf16x8 b0 = *(const bf16x8*)(&Bls[z][row * 64 + ((quad ^ (row & 7)) * 8)]);
                bf16x8 b1 = *(const bf16x8*)(&Bls[z][row * 64 + (((4 + quad) ^ (row & 7)) * 8)]);
#pragma unroll
                for (int ii = 0; ii < 2; ++ii) {
                    acc[z][ii][jj] = __builtin_amdgcn_mfma_f32_16x16x32_bf16(af[ii][0], b0, acc[z][ii][jj], 0, 0, 0);
                    acc[z][ii][jj] = __builtin_amdgcn_mfma_f32_16x16x32_bf16(af[ii][1], b1, acc[z][ii][jj], 0, 0, 0);
                }
            }
        }
    }

    // ---- epilogues ----
    const int dlo = 16 * wn2 + c0;              // jj=0 -> d = dlo (<32); jj=1 -> d = dlo+32
    // Q and K: bias + RoPE (+ Q scale), layout (BH,S,D)
#pragma unroll
    for (int z = 0; z < 2; ++z) {
        const float* bias = z ? bk : bq;
        __bf16* Cout = (__bf16*)(qkv_out + (size_t)z * QELEM);
        float b0 = bias[n0 + dlo], b1 = bias[n0 + dlo + 32];
#pragma unroll
        for (int ii = 0; ii < 2; ++ii) {
#pragma unroll
            for (int r = 0; r < 4; ++r) {
                int m = m0 + wm + 16 * ii + quad * 4 + r;
                int b = m >> 11, s = m & (S_LEN - 1);
                float lo = acc[z][ii][0][r] + b0;
                float hi = acc[z][ii][1][r] + b1;
                float2 t = rope[s * 32 + dlo];
                float v0 = lo * t.x - hi * t.y;
                float v1 = hi * t.x + lo * t.y;
                if (z == 0) { v0 *= 0.18033688011112042f; v1 *= 0.18033688011112042f; }
                __bf16* row = Cout + ((size_t)(b * NH + h) * S_LEN + s) * DH;
                row[dlo]      = (__bf16)v0;
                row[dlo + 32] = (__bf16)v1;
            }
        }
    }
    // V: bias only, transposed store (BH,D,S); pack 4 consecutive s per 8B store
    {
        __bf16* Cout = (__bf16*)(qkv_out + (size_t)2 * QELEM);
        float b0 = bv[n0 + dlo], b1 = bv[n0 + dlo + 32];
#pragma unroll
        for (int ii = 0; ii < 2; ++ii) {
            int m = m0 + wm + 16 * ii + quad * 4;
            int b = m >> 11, s = m & (S_LEN - 1);
            bf16x4 p0, p1;
#pragma unroll
            for (int r = 0; r < 4; ++r) {
                p0[r] = (__bf16)(acc[2][ii][0][r] + b0);
                p1[r] = (__bf16)(acc[2][ii][1][r] + b1);
            }
            *(bf16x4*)(Cout + ((size_t)(b * NH + h) * DH + dlo)      * S_LEN + s) = p0;
            *(bf16x4*)(Cout + ((size_t)(b * NH + h) * DH + dlo + 32) * S_LEN + s) = p1;
        }
    }
}

// ---------------- causal flash attention, 32x32 MFMA, n-split waves, P-in-register ----------------
// (R8 best-measured version, unchanged.)
__global__ __launch_bounds__(256, 3) void flash_kernel(
    const unsigned short* __restrict__ Qg, const unsigned short* __restrict__ Kg,
    const unsigned short* __restrict__ Vt, unsigned short* __restrict__ Og)
{
    __shared__ __align__(16) unsigned short Kls[3][64 * 64];   // [s][d], chunk-swizzled
    __shared__ __align__(16) unsigned short Vls[3][64 * 64];   // [d][s], chunk-swizzled
    __shared__ float lred[2][64];

    // snake schedule: CU triples {i, i+256, i+512} get ~equal causal work
    const int i = blockIdx.x;
    const int kk = i >> 8, g = i & 255;
    const int r0 = (kk == 0) ? g : (kk == 1 ? 511 - g : 512 + g);
    const int qt = 31 - r0 / 24;
    const int bh = r0 % 24;
    const int b = bh / NH, h = bh % NH;
    const int m0 = qt * 64;
    const int tid = threadIdx.x, lane = tid & 63, wave = tid >> 6;
    const int wm2 = wave >> 1, wn2 = wave & 1;
    const int lr = lane & 31, hf = lane >> 5;
    const size_t base = (size_t)bh * S_LEN * DH;
    const int mrow = m0 + wm2 * 32 + lr;      // this lane's m (S column / Q row)

    // Q-frags (B-operand of 32x32x16): col m = lr, k = d = 16t + 8*hf + j
    bf16x8 qf[4];
#pragma unroll
    for (int t = 0; t < 4; ++t)
        qf[t] = *(const bf16x8*)(Qg + base + (size_t)mrow * DH + 16 * t + 8 * hf);
    asm volatile("" :: "v"(qf[0]), "v"(qf[1]), "v"(qf[2]), "v"(qf[3]));

    floatx16 oa0 = {}, oa1 = {};               // O^T partial: col m = lr, row d = (r&3)+8*(r>>2)+4*hf (+32 for oa1)
    float l_lane = 0.f;
    const float C = 23.083120654223414f;       // 16*log2(e): constant "max" (scores bounded << 16)
    const int ntiles = qt + 1;

    // stage: 4 gl_lds16 per thread per tile (2 K + 2 V) — the vmcnt bookkeeping unit
#define STAGE_TILE(T, BUF)                                                              \
    {                                                                                   \
        _Pragma("unroll")                                                               \
        for (int it = 0; it < 2; ++it) {                                                \
            int ch = it * 256 + tid;                                                    \
            int row = ch >> 3, cc = (ch & 7) ^ (row & 7);                               \
            gl_lds16(Kg + base + (size_t)((T) * 64 + row) * DH + cc * 8,                \
                     &Kls[BUF][ch * 8]);                                                \
            gl_lds16(Vt + base + (size_t)row * S_LEN + (T) * 64 + cc * 8,               \
                     &Vls[BUF][ch * 8]);                                                \
        }                                                                               \
    }

    STAGE_TILE(0, 0);
    if (ntiles > 1) STAGE_TILE(1, 1);

    for (int nt = 0; nt < ntiles; ++nt) {
        const int buf = nt % 3;
        if (nt + 1 < ntiles) asm volatile("s_waitcnt vmcnt(4)" ::: "memory");
        else                 asm volatile("s_waitcnt vmcnt(0)" ::: "memory");
        __builtin_amdgcn_s_barrier();          // all waves' stage(nt) landed
        asm volatile("" ::: "memory");         // fence: no LDS reads/stage hoisted above
        if (nt + 2 < ntiles) STAGE_TILE(nt + 2, (nt + 2) % 3);
        const unsigned short* Kb = Kls[buf];
        const unsigned short* Vb = Vls[buf];

        // S^T chunk = K(32n) · Q^T(32m), K-dim d=64 -> 4 MFMAs. A row n = wn2*32+lr.
        floatx16 sa = {};
        __builtin_amdgcn_s_setprio(1);
#pragma unroll
        for (int t = 0; t < 4; ++t) {
            int row = wn2 * 32 + lr;
            int ck = (2 * t + hf) ^ (row & 7);
            bf16x8 kf = *(const bf16x8*)(Kb + row * 64 + ck * 8);
            sa = __builtin_amdgcn_mfma_f32_32x32x16_bf16(kf, qf[t], sa, 0, 0, 0);
        }
        __builtin_amdgcn_s_setprio(0);

        if (nt == ntiles - 1) {                // causal mask, diagonal tile only
#pragma unroll
            for (int r = 0; r < 16; ++r) {
                int n = nt * 64 + wn2 * 32 + (r & 3) + 8 * (r >> 2) + 4 * hf;
                if (n > mrow) sa[r] = -1e30f;
            }
        }

        // p = exp2(s - C) packed straight to bf16 word-pairs (n ascending in r)
        unsigned W[8];
#pragma unroll
        for (int q = 0; q < 8; ++q) {
            float p0 = __builtin_amdgcn_exp2f(sa[2 * q] - C);
            float p1 = __builtin_amdgcn_exp2f(sa[2 * q + 1] - C);
            l_lane += p0 + p1;
            union { __bf16 bb[2]; unsigned u; } w;
            w.bb[0] = (__bf16)p0; w.bb[1] = (__bf16)p1;
            W[q] = w.u;
        }
        // PV B-frags: k = n_local = 16*t2 + 8*hf + j. Half-swap via shfl_xor(32).
        bf16x8 pb[2];
#pragma unroll
        for (int t2 = 0; t2 < 2; ++t2) {
            unsigned own0 = hf ? W[4 * t2 + 2] : W[4 * t2 + 0];
            unsigned own1 = hf ? W[4 * t2 + 3] : W[4 * t2 + 1];
            unsigned giv0 = hf ? W[4 * t2 + 0] : W[4 * t2 + 2];
            unsigned giv1 = hf ? W[4 * t2 + 1] : W[4 * t2 + 3];
            unsigned s0 = (unsigned)__shfl_xor((int)giv0, 32, 64);
            unsigned s1 = (unsigned)__shfl_xor((int)giv1, 32, 64);
            union { unsigned u[4]; bf16x8 v; } pk;
            pk.u[0] = hf ? s0 : own0;          // words from half 0
            pk.u[1] = hf ? s1 : own1;
            pk.u[2] = hf ? own0 : s0;          // words from half 1
            pk.u[3] = hf ? own1 : s1;
            pb[t2] = pk.v;
        }

        // O^T += V^T(32d x 32n) · P(32n x 32m); A row d = 32*dt+lr, k = n_local
        __builtin_amdgcn_s_setprio(1);
#pragma unroll
        for (int dt = 0; dt < 2; ++dt) {
            int d = 32 * dt + lr;
#pragma unroll
            for (int t2 = 0; t2 < 2; ++t2) {
                int cv = (wn2 * 4 + 2 * t2 + hf) ^ (d & 7);
                bf16x8 vf = *(const bf16x8*)(Vb + d * 64 + cv * 8);
                if (dt == 0) oa0 = __builtin_amdgcn_mfma_f32_32x32x16_bf16(vf, pb[t2], oa0, 0, 0, 0);
                else         oa1 = __builtin_amdgcn_mfma_f32_32x32x16_bf16(vf, pb[t2], oa1, 0, 0, 0);
            }
        }
        __builtin_amdgcn_s_setprio(0);
    }
#undef STAGE_TILE

    // combine halves of l (lanes l and l^32 hold same m, disjoint n)
    l_lane += __shfl_xor(l_lane, 32, 64);

    // cross-wave (wn2 pair) O/l reduction via LDS scratch (aliases Kls; all staging done)
    __syncthreads();
    float* red = (float*)&Kls[0][0];           // [64][64] f32 = 16KB
    if (wn2 == 1) {
#pragma unroll
        for (int e = 0; e < 16; ++e) red[(wm2 * 32 + e) * 64 + lane]        = oa0[e];
#pragma unroll
        for (int e = 0; e < 16; ++e) red[(wm2 * 32 + 16 + e) * 64 + lane]   = oa1[e];
        lred[wm2][lane] = l_lane;
    }
    __syncthreads();
    if (wn2 == 0) {
        const float lt = l_lane + lred[wm2][lane];
        const float rl = 1.0f / lt;
        __bf16* Ob16 = (__bf16*)Og;
#pragma unroll
        for (int rg = 0; rg < 4; ++rg) {       // reg groups of 4: d = 8*rg + 4*hf (+32 for oa1)
            bf16x4 ov0, ov1;
#pragma unroll
            for (int j = 0; j < 4; ++j) {
                int e = rg * 4 + j;
                ov0[j] = (__bf16)((oa0[e] + red[(wm2 * 32 + e) * 64 + lane]) * rl);
                ov1[j] = (__bf16)((oa1[e] + red[(wm2 * 32 + 16 + e) * 64 + lane]) * rl);
            }
            int d = 8 * rg + 4 * hf;
            *(bf16x4*)(Ob16 + ((size_t)(b * S_LEN + mrow)) * EMB + h * DH + d)      = ov0;
            *(bf16x4*)(Ob16 + ((size_t)(b * S_LEN + mrow)) * EMB + h * DH + 32 + d) = ov1;
        }
    }
}

// ---------------- output projection: fp32 out; 64x64 tiles -> 768 blocks (3/CU) ----------------
__global__ __launch_bounds__(256, 4) void proj_kernel(
    const unsigned short* __restrict__ Ob, const unsigned short* __restrict__ WpT,
    const float* __restrict__ bp, float* __restrict__ out)
{
    __shared__ __align__(16) unsigned short Als[64 * 64];
    __shared__ __align__(16) unsigned short Bls[64 * 64];
    const int m0 = blockIdx.x * 64, n0 = blockIdx.y * 64;
    const int tid = threadIdx.x, lane = tid & 63, c0 = lane & 15, quad = lane >> 4, wave = tid >> 6;
    const int wm = (wave >> 1) * 32, wn = (wave & 1) * 32;

    floatx4 acc[2][2] = {};
    gemm_core<64, 64, 32, 32>(Ob, WpT, m0, n0, EMB, tid, acc, Als, Bls);

#pragma unroll
    for (int ii = 0; ii < 2; ++ii)
#pragma unroll
        for (int r = 0; r < 4; ++r) {
            int m = m0 + wm + 16 * ii + quad * 4 + r;
#pragma unroll
            for (int jj = 0; jj < 2; ++jj) {
                int n = n0 + wn + 16 * jj + c0;
                out[(size_t)m * EMB + n] = acc[ii][jj][r] + bp[n];
            }
        }
}

extern "C" void kernel_launch(void* const* d_in, const int* in_sizes, int n_in,
                              void* d_out, int out_size, void* d_ws, size_t ws_size,
                              hipStream_t stream)
{
    (void)in_sizes; (void)n_in; (void)out_size;
    const float* x  = (const float*)d_in[0];
    const float* Wq = (const float*)d_in[1];
    const float* bq = (const float*)d_in[2];
    const float* Wk = (const float*)d_in[3];
    const float* bk = (const float*)d_in[4];
    const float* Wv = (const float*)d_in[5];
    const float* bv = (const float*)d_in[6];
    const float* Wp = (const float*)d_in[7];
    const float* bp = (const float*)d_in[8];

    unsigned short* ws  = (unsigned short*)d_ws;
    unsigned short* xb  = ws;                                   // QELEM
    unsigned short* WT  = xb + (size_t)QELEM;                   // 4*WELEM  (WqT,WkT,WvT,WpT)
    unsigned short* QKV = WT + 4 * (size_t)WELEM;               // 3*QELEM  (Q,K,V^T)
    unsigned short* Ob  = QKV + 3 * (size_t)QELEM;              // QELEM
    float2* rope = (float2*)(Ob + (size_t)QELEM);               // 2048*32 float2 = 512KB
    if (ws_size < ((size_t)QELEM * 5 + 4 * (size_t)WELEM) * 2 + 2048 * 32 * 8) return;

    cvt_all_kernel<<<3904, 256, 0, stream>>>(x, xb, Wq, Wk, Wv, Wp, WT, rope);
    qkv_kernel<<<dim3(64, 12), 256, 0, stream>>>(xb, WT, bq, bk, bv, (const float2*)rope, QKV);
    flash_kernel<<<dim3(768), 256, 0, stream>>>(QKV, QKV + QELEM, QKV + 2 * (size_t)QELEM, Ob);
    proj_kernel<<<dim3(64, 12), 256, 0, stream>>>(Ob, WT + 3 * (size_t)WELEM, bp, (float*)d_out);
}